// Round 3
// baseline (1291.910 us; speedup 1.0000x reference)
//
#include <hip/hip_runtime.h>

#define N_NODES 100000
#define IN_CH 16
#define HIDDEN 32
#define NUM_HH 1000

#define NPB 128                                   // nodes per bucket
#define NBUCK ((N_NODES + NPB - 1) / NPB)         // 782
#define NCHUNK 512                                // edge chunks (pass A/B blocks)
#define SCAN_N (NBUCK * NCHUNK)                   // 400384
#define S1_BLOCKS ((SCAN_N + 1023) / 1024)        // 391

// ---------------------------------------------------------------------------
// Pass A: per-chunk bucket histogram (LDS), write counts[bucket][chunk].
// ---------------------------------------------------------------------------
__global__ __launch_bounds__(256) void passA_count(const int* __restrict__ dst,
                                                   int* __restrict__ counts,
                                                   int n_edges, int cepb) {
  __shared__ int hist[NBUCK];
  for (int i = threadIdx.x; i < NBUCK; i += 256) hist[i] = 0;
  __syncthreads();
  const int s = blockIdx.x * cepb;
  const int e = min(n_edges, s + cepb);
  for (int i = s + threadIdx.x; i < e; i += 256)
    atomicAdd(&hist[dst[i] >> 7], 1);
  __syncthreads();
  for (int i = threadIdx.x; i < NBUCK; i += 256)
    counts[i * NCHUNK + blockIdx.x] = hist[i];
}

// ---------------------------------------------------------------------------
// Exclusive scan over SCAN_N ints (bucket-major order).
// ---------------------------------------------------------------------------
__global__ __launch_bounds__(1024) void scan_local(const int* __restrict__ in,
                                                   int* __restrict__ out,
                                                   int* __restrict__ partials) {
  __shared__ int tmp[1024];
  const int i = blockIdx.x * 1024 + threadIdx.x;
  const int v = (i < SCAN_N) ? in[i] : 0;
  tmp[threadIdx.x] = v;
  __syncthreads();
  for (int off = 1; off < 1024; off <<= 1) {
    int t = (threadIdx.x >= off) ? tmp[threadIdx.x - off] : 0;
    __syncthreads();
    tmp[threadIdx.x] += t;
    __syncthreads();
  }
  if (i < SCAN_N) out[i] = tmp[threadIdx.x] - v;  // exclusive
  if (threadIdx.x == 1023) partials[blockIdx.x] = tmp[threadIdx.x];
}

__global__ __launch_bounds__(512) void scan_partials(int* __restrict__ partials) {
  __shared__ int tmp[512];
  const int v = (threadIdx.x < S1_BLOCKS) ? partials[threadIdx.x] : 0;
  tmp[threadIdx.x] = v;
  __syncthreads();
  for (int off = 1; off < 512; off <<= 1) {
    int t = (threadIdx.x >= off) ? tmp[threadIdx.x - off] : 0;
    __syncthreads();
    tmp[threadIdx.x] += t;
    __syncthreads();
  }
  if (threadIdx.x < S1_BLOCKS) partials[threadIdx.x] = tmp[threadIdx.x] - v;
}

__global__ __launch_bounds__(1024) void scan_add(int* __restrict__ out,
                                                 const int* __restrict__ partials,
                                                 int* __restrict__ bucket_ptr,
                                                 int n_edges) {
  const int i = blockIdx.x * 1024 + threadIdx.x;
  if (i < SCAN_N) {
    const int v = out[i] + partials[blockIdx.x];
    out[i] = v;
    if ((i & (NCHUNK - 1)) == 0) bucket_ptr[i / NCHUNK] = v;
  }
  if (i == 0) bucket_ptr[NBUCK] = n_edges;
}

// ---------------------------------------------------------------------------
// Pass B: scatter packed (src | local<<17) into per-(bucket,chunk) regions.
// ---------------------------------------------------------------------------
__global__ __launch_bounds__(256) void passB_scatter(
    const int* __restrict__ src, const int* __restrict__ dst,
    const int* __restrict__ offs, unsigned* __restrict__ packed, int n_edges,
    int cepb) {
  __shared__ int cur[NBUCK];
  for (int i = threadIdx.x; i < NBUCK; i += 256)
    cur[i] = offs[i * NCHUNK + blockIdx.x];
  __syncthreads();
  const int s = blockIdx.x * cepb;
  const int e = min(n_edges, s + cepb);
  for (int i = s + threadIdx.x; i < e; i += 256) {
    const int d = dst[i];
    const int b = d >> 7;
    const int pos = atomicAdd(&cur[b], 1);
    packed[pos] = (unsigned)src[i] | ((unsigned)(d & (NPB - 1)) << 17);
  }
}

// ---------------------------------------------------------------------------
// Fused SAGE layer, one block per bucket:
//   LDS-accumulate sum of feat[src] per local node (+degree), then
//   out[n] = relu(mean @ w_l + b + feat[n] @ w_r) via in-LDS GEMV.
// ---------------------------------------------------------------------------
template <int CH>
__global__ __launch_bounds__(512) void sage_agg(
    const float* __restrict__ feat, const unsigned* __restrict__ packed,
    const int* __restrict__ bucket_ptr, const float* __restrict__ w_l,
    const float* __restrict__ w_r, const float* __restrict__ bias,
    float* __restrict__ out) {
  __shared__ float acc[NPB][CH + 1];
  __shared__ int degs[NPB];
  __shared__ float wl[CH * HIDDEN];
  __shared__ float wr[CH * HIDDEN];
  __shared__ float bs[HIDDEN];

  const int tid = threadIdx.x;
  for (int i = tid; i < NPB * (CH + 1); i += 512) ((float*)acc)[i] = 0.0f;
  for (int i = tid; i < NPB; i += 512) degs[i] = 0;
  for (int i = tid; i < CH * HIDDEN; i += 512) {
    wl[i] = w_l[i];
    wr[i] = w_r[i];
  }
  if (tid < HIDDEN) bs[tid] = bias[tid];
  __syncthreads();

  const int b = blockIdx.x;
  const int base = b * NPB;
  const int nvalid = min(NPB, N_NODES - base);
  const int s = bucket_ptr[b];
  const int e = bucket_ptr[b + 1];

  constexpr int Q = CH / 4;        // lanes per edge
  constexpr int GP = 512 / Q;      // edges in flight per iteration
  const int q = tid & (Q - 1);
  const int g = tid / Q;

  for (int i = s + g; i < e; i += GP) {
    const unsigned pk = packed[i];
    const int sn = pk & 0x1FFFF;
    const int l = pk >> 17;
    const float4 v = ((const float4*)(feat + (size_t)sn * CH))[q];
    atomicAdd(&acc[l][4 * q + 0], v.x);
    atomicAdd(&acc[l][4 * q + 1], v.y);
    atomicAdd(&acc[l][4 * q + 2], v.z);
    atomicAdd(&acc[l][4 * q + 3], v.w);
    if (q == 0) atomicAdd(&degs[l], 1);
  }
  __syncthreads();

  // GEMV: 4 threads per node, 8 output channels each.
  const int l = tid >> 2;
  const int quarter = tid & 3;
  if (l < nvalid) {
    const int node = base + l;
    const float inv = 1.0f / fmaxf((float)degs[l], 1.0f);

    float xv[CH];
    const float4* xr = (const float4*)(feat + (size_t)node * CH);
#pragma unroll
    for (int k4 = 0; k4 < CH / 4; ++k4) {
      const float4 t = xr[k4];
      xv[4 * k4 + 0] = t.x;
      xv[4 * k4 + 1] = t.y;
      xv[4 * k4 + 2] = t.z;
      xv[4 * k4 + 3] = t.w;
    }

    float o[8];
#pragma unroll
    for (int j = 0; j < 8; ++j) o[j] = bs[quarter * 8 + j];

#pragma unroll
    for (int k = 0; k < CH; ++k) {
      const float mk = acc[l][k] * inv;
      const float4* wl4 = (const float4*)(wl + k * HIDDEN + quarter * 8);
      const float4* wr4 = (const float4*)(wr + k * HIDDEN + quarter * 8);
#pragma unroll
      for (int j4 = 0; j4 < 2; ++j4) {
        const float4 a = wl4[j4];
        const float4 r = wr4[j4];
        o[4 * j4 + 0] = fmaf(mk, a.x, fmaf(xv[k], r.x, o[4 * j4 + 0]));
        o[4 * j4 + 1] = fmaf(mk, a.y, fmaf(xv[k], r.y, o[4 * j4 + 1]));
        o[4 * j4 + 2] = fmaf(mk, a.z, fmaf(xv[k], r.z, o[4 * j4 + 2]));
        o[4 * j4 + 3] = fmaf(mk, a.w, fmaf(xv[k], r.w, o[4 * j4 + 3]));
      }
    }

    float4* o4 = (float4*)(out + (size_t)node * HIDDEN + quarter * 8);
#pragma unroll
    for (int j4 = 0; j4 < 2; ++j4) {
      float4 v;
      v.x = fmaxf(o[4 * j4 + 0], 0.0f);
      v.y = fmaxf(o[4 * j4 + 1], 0.0f);
      v.z = fmaxf(o[4 * j4 + 2], 0.0f);
      v.w = fmaxf(o[4 * j4 + 3], 0.0f);
      o4[j4] = v;
    }
  }
}

// ---------------------------------------------------------------------------
// FC head: out[N,1000] = h[N,32] @ fc_w[32,1000] + fc_b
// ---------------------------------------------------------------------------
#define FC_BN 128
__global__ __launch_bounds__(256) void fc_kernel(
    const float* __restrict__ h, const float* __restrict__ fcw,
    const float* __restrict__ fcb, float* __restrict__ out) {
  __shared__ float hs[FC_BN * HIDDEN];
  int base = blockIdx.x * FC_BN;
  int nvalid = min(FC_BN, N_NODES - base);

  int cnt4 = nvalid * HIDDEN / 4;
  const float4* s4 = (const float4*)(h + (size_t)base * HIDDEN);
  for (int i = threadIdx.x; i < cnt4; i += 256) ((float4*)hs)[i] = s4[i];
  __syncthreads();

#pragma unroll
  for (int c = 0; c < 4; ++c) {
    int j = c * 256 + threadIdx.x;
    if (j < NUM_HH) {
      float w[HIDDEN];
#pragma unroll
      for (int k = 0; k < HIDDEN; ++k) w[k] = fcw[k * NUM_HH + j];
      float bias = fcb[j];
      int n = 0;
      for (; n + 2 <= nvalid; n += 2) {
        float a0 = bias, a1 = bias;
#pragma unroll
        for (int k = 0; k < HIDDEN; ++k) {
          a0 = fmaf(hs[n * HIDDEN + k], w[k], a0);
          a1 = fmaf(hs[(n + 1) * HIDDEN + k], w[k], a1);
        }
        out[(size_t)(base + n) * NUM_HH + j] = a0;
        out[(size_t)(base + n + 1) * NUM_HH + j] = a1;
      }
      for (; n < nvalid; ++n) {
        float a0 = bias;
#pragma unroll
        for (int k = 0; k < HIDDEN; ++k)
          a0 = fmaf(hs[n * HIDDEN + k], w[k], a0);
        out[(size_t)(base + n) * NUM_HH + j] = a0;
      }
    }
  }
}

extern "C" void kernel_launch(void* const* d_in, const int* in_sizes, int n_in,
                              void* d_out, int out_size, void* d_ws,
                              size_t ws_size, hipStream_t stream) {
  const float* x = (const float*)d_in[0];
  const int* edge = (const int*)d_in[1];
  const float* w1_l = (const float*)d_in[2];
  const float* w1_r = (const float*)d_in[3];
  const float* b1 = (const float*)d_in[4];
  const float* w2_l = (const float*)d_in[5];
  const float* w2_r = (const float*)d_in[6];
  const float* b2 = (const float*)d_in[7];
  const float* fc_w = (const float*)d_in[8];
  const float* fc_b = (const float*)d_in[9];
  float* out = (float*)d_out;

  const int n_edges = in_sizes[1] / 2;
  const int* src = edge;
  const int* dst = edge + n_edges;

  // Workspace: packed[E] | h1[N*32] | h2[N*32] | bucket_ptr[NBUCK+1] | partials
  // counts/offs (3.2 MB) alias the head of h2 (dead until sage_agg<32> writes it).
  unsigned* packed = (unsigned*)d_ws;
  float* h1 = (float*)(packed + n_edges);
  float* h2 = h1 + (size_t)N_NODES * HIDDEN;
  int* counts = (int*)h2;          // alias, dead after scan_local
  int* offs = counts + SCAN_N;     // alias, dead after passB_scatter
  int* bucket_ptr = (int*)(h2 + (size_t)N_NODES * HIDDEN);
  int* partials = bucket_ptr + NBUCK + 1;

  const int cepb = (n_edges + NCHUNK - 1) / NCHUNK;
  const int fgrid = (N_NODES + FC_BN - 1) / FC_BN;

  // ---- bucket partition (shared by both layers) ----
  passA_count<<<NCHUNK, 256, 0, stream>>>(dst, counts, n_edges, cepb);
  scan_local<<<S1_BLOCKS, 1024, 0, stream>>>(counts, offs, partials);
  scan_partials<<<1, 512, 0, stream>>>(partials);
  scan_add<<<S1_BLOCKS, 1024, 0, stream>>>(offs, partials, bucket_ptr, n_edges);
  passB_scatter<<<NCHUNK, 256, 0, stream>>>(src, dst, offs, packed, n_edges,
                                            cepb);

  // ---- Layer 1 (CH=16): x -> h1 ----
  sage_agg<IN_CH><<<NBUCK, 512, 0, stream>>>(x, packed, bucket_ptr, w1_l, w1_r,
                                             b1, h1);
  // ---- Layer 2 (CH=32): h1 -> h2 (overwrites counts/offs alias, now dead) ----
  sage_agg<HIDDEN><<<NBUCK, 512, 0, stream>>>(h1, packed, bucket_ptr, w2_l,
                                              w2_r, b2, h2);
  // ---- FC head ----
  fc_kernel<<<fgrid, 256, 0, stream>>>(h2, fc_w, fc_b, out);
}

// Round 4
// 436.901 us; speedup vs baseline: 2.9570x; 2.9570x over previous
//
#include <hip/hip_runtime.h>

#define N_NODES 100000
#define IN_CH 16
#define HIDDEN 32
#define NUM_HH 1000

#define NPB 128                                   // nodes per bucket
#define NBUCK ((N_NODES + NPB - 1) / NPB)         // 782
#define NCHUNK 512                                // edge chunks (pass A/B blocks)
#define SCAN_N (NBUCK * NCHUNK)                   // 400384
#define S1_BLOCKS ((SCAN_N + 1023) / 1024)        // 391
#define SORT_CAP 6144                             // bucket mean 4096, std ~64

// ---------------------------------------------------------------------------
// Pass A: per-chunk bucket histogram (LDS), write counts[bucket][chunk].
// ---------------------------------------------------------------------------
__global__ __launch_bounds__(256) void passA_count(const int* __restrict__ dst,
                                                   int* __restrict__ counts,
                                                   int n_edges, int cepb) {
  __shared__ int hist[NBUCK];
  for (int i = threadIdx.x; i < NBUCK; i += 256) hist[i] = 0;
  __syncthreads();
  const int s = blockIdx.x * cepb;
  const int e = min(n_edges, s + cepb);
  for (int i = s + threadIdx.x; i < e; i += 256)
    atomicAdd(&hist[dst[i] >> 7], 1);
  __syncthreads();
  for (int i = threadIdx.x; i < NBUCK; i += 256)
    counts[i * NCHUNK + blockIdx.x] = hist[i];
}

// ---------------------------------------------------------------------------
// Exclusive scan over SCAN_N ints (bucket-major order).
// ---------------------------------------------------------------------------
__global__ __launch_bounds__(1024) void scan_local(const int* __restrict__ in,
                                                   int* __restrict__ out,
                                                   int* __restrict__ partials) {
  __shared__ int tmp[1024];
  const int i = blockIdx.x * 1024 + threadIdx.x;
  const int v = (i < SCAN_N) ? in[i] : 0;
  tmp[threadIdx.x] = v;
  __syncthreads();
  for (int off = 1; off < 1024; off <<= 1) {
    int t = (threadIdx.x >= off) ? tmp[threadIdx.x - off] : 0;
    __syncthreads();
    tmp[threadIdx.x] += t;
    __syncthreads();
  }
  if (i < SCAN_N) out[i] = tmp[threadIdx.x] - v;  // exclusive
  if (threadIdx.x == 1023) partials[blockIdx.x] = tmp[threadIdx.x];
}

__global__ __launch_bounds__(512) void scan_partials(int* __restrict__ partials) {
  __shared__ int tmp[512];
  const int v = (threadIdx.x < S1_BLOCKS) ? partials[threadIdx.x] : 0;
  tmp[threadIdx.x] = v;
  __syncthreads();
  for (int off = 1; off < 512; off <<= 1) {
    int t = (threadIdx.x >= off) ? tmp[threadIdx.x - off] : 0;
    __syncthreads();
    tmp[threadIdx.x] += t;
    __syncthreads();
  }
  if (threadIdx.x < S1_BLOCKS) partials[threadIdx.x] = tmp[threadIdx.x] - v;
}

__global__ __launch_bounds__(1024) void scan_add(int* __restrict__ out,
                                                 const int* __restrict__ partials,
                                                 int* __restrict__ bucket_ptr,
                                                 int n_edges) {
  const int i = blockIdx.x * 1024 + threadIdx.x;
  if (i < SCAN_N) {
    const int v = out[i] + partials[blockIdx.x];
    out[i] = v;
    if ((i & (NCHUNK - 1)) == 0) bucket_ptr[i / NCHUNK] = v;
  }
  if (i == 0) bucket_ptr[NBUCK] = n_edges;
}

// ---------------------------------------------------------------------------
// Pass B: scatter packed (src | local<<17) into per-(bucket,chunk) regions.
// ---------------------------------------------------------------------------
__global__ __launch_bounds__(256) void passB_scatter(
    const int* __restrict__ src, const int* __restrict__ dst,
    const int* __restrict__ offs, unsigned* __restrict__ packed, int n_edges,
    int cepb) {
  __shared__ int cur[NBUCK];
  for (int i = threadIdx.x; i < NBUCK; i += 256)
    cur[i] = offs[i * NCHUNK + blockIdx.x];
  __syncthreads();
  const int s = blockIdx.x * cepb;
  const int e = min(n_edges, s + cepb);
  for (int i = s + threadIdx.x; i < e; i += 256) {
    const int d = dst[i];
    const int b = d >> 7;
    const int pos = atomicAdd(&cur[b], 1);
    packed[pos] = (unsigned)src[i] | ((unsigned)(d & (NPB - 1)) << 17);
  }
}

// ---------------------------------------------------------------------------
// Bucket sort: one block per bucket. Stage the bucket's packed entries in
// LDS, 128-bin counting sort, scatter back IN PLACE (now sorted by local
// node, value = src only). Emits node-level row_ptr.
// ---------------------------------------------------------------------------
__global__ __launch_bounds__(512) void bucket_sort(
    unsigned* __restrict__ packed, const int* __restrict__ bucket_ptr,
    int* __restrict__ row_ptr, int n_edges) {
  __shared__ unsigned stage[SORT_CAP];
  __shared__ int bins[NPB];
  __shared__ int scn[NPB];
  __shared__ int cur[NPB];
  const int b = blockIdx.x;
  const int s = bucket_ptr[b];
  const int cnt = bucket_ptr[b + 1] - s;
  const int tid = threadIdx.x;

  if (tid < NPB) bins[tid] = 0;
  __syncthreads();
  for (int i = tid; i < cnt; i += 512) {
    const unsigned pk = packed[s + i];
    stage[i] = pk;
    atomicAdd(&bins[pk >> 17], 1);
  }
  __syncthreads();
  if (tid < NPB) scn[tid] = bins[tid];
  __syncthreads();
  for (int off = 1; off < NPB; off <<= 1) {
    int t = (tid < NPB && tid >= off) ? scn[tid - off] : 0;
    __syncthreads();
    if (tid < NPB) scn[tid] += t;
    __syncthreads();
  }
  if (tid < NPB) {
    const int excl = scn[tid] - bins[tid];
    cur[tid] = excl;
    const int node = b * NPB + tid;
    if (node < N_NODES) row_ptr[node] = s + excl;
  }
  if (b == NBUCK - 1 && tid == 0) row_ptr[N_NODES] = n_edges;
  __syncthreads();
  for (int i = tid; i < cnt; i += 512) {
    const unsigned pk = stage[i];
    const int pos = atomicAdd(&cur[pk >> 17], 1);
    packed[s + pos] = pk & 0x1FFFFu;  // sorted; strip local bits
  }
}

// ---------------------------------------------------------------------------
// Fused SAGE layer: one wave per node (proven in round 2).
// Phase 1: lanes gather feat[adj[i]] quads, shfl_xor butterfly -> mean in LDS.
// Phase 2: in-wave GEMV: out = relu(mean@w_l + x@w_r + b).
// ---------------------------------------------------------------------------
template <int CH>
__global__ __launch_bounds__(256) void sage_fused(
    const float* __restrict__ feat, const int* __restrict__ row_ptr,
    const int* __restrict__ adj, const float* __restrict__ w_l,
    const float* __restrict__ w_r, const float* __restrict__ b,
    float* __restrict__ out) {
  constexpr int Q = CH / 4;    // float4 quads per node row
  constexpr int EPW = 64 / Q;  // edges gathered per wave iteration
  __shared__ float wl[CH * HIDDEN];
  __shared__ float wr[CH * HIDDEN];
  __shared__ float bs[HIDDEN];
  __shared__ float mean_s[4][CH];
  __shared__ float xs[4][CH];
  for (int i = threadIdx.x; i < CH * HIDDEN; i += 256) {
    wl[i] = w_l[i];
    wr[i] = w_r[i];
  }
  if (threadIdx.x < HIDDEN) bs[threadIdx.x] = b[threadIdx.x];

  const int wave = threadIdx.x >> 6;
  const int lane = threadIdx.x & 63;
  const int n = blockIdx.x * 4 + wave;  // grid sized so n < N_NODES always

  const int s = row_ptr[n];
  const int e = row_ptr[n + 1];
  const int q = lane % Q;
  const int esub = lane / Q;

  float4 acc = {0.f, 0.f, 0.f, 0.f};
  for (int i = s + esub; i < e; i += EPW) {
    const float4 v = ((const float4*)(feat + (size_t)adj[i] * CH))[q];
    acc.x += v.x;
    acc.y += v.y;
    acc.z += v.z;
    acc.w += v.w;
  }
#pragma unroll
  for (int m = Q; m < 64; m <<= 1) {
    acc.x += __shfl_xor(acc.x, m, 64);
    acc.y += __shfl_xor(acc.y, m, 64);
    acc.z += __shfl_xor(acc.z, m, 64);
    acc.w += __shfl_xor(acc.w, m, 64);
  }
  const float inv = 1.0f / fmaxf((float)(e - s), 1.0f);
  if (esub == 0) {  // lane == q
    mean_s[wave][4 * q + 0] = acc.x * inv;
    mean_s[wave][4 * q + 1] = acc.y * inv;
    mean_s[wave][4 * q + 2] = acc.z * inv;
    mean_s[wave][4 * q + 3] = acc.w * inv;
    const float4 xv = ((const float4*)(feat + (size_t)n * CH))[q];
    xs[wave][4 * q + 0] = xv.x;
    xs[wave][4 * q + 1] = xv.y;
    xs[wave][4 * q + 2] = xv.z;
    xs[wave][4 * q + 3] = xv.w;
  }
  __syncthreads();

  const int j = lane & 31;
  const int p = lane >> 5;  // half-wave splits the k range
  float o = 0.f;
#pragma unroll
  for (int k = p * (CH / 2); k < (p + 1) * (CH / 2); ++k)
    o = fmaf(mean_s[wave][k], wl[k * HIDDEN + j],
             fmaf(xs[wave][k], wr[k * HIDDEN + j], o));
  o += __shfl_xor(o, 32, 64);
  if (p == 0) out[(size_t)n * HIDDEN + j] = fmaxf(o + bs[j], 0.f);
}

// ---------------------------------------------------------------------------
// FC head: out[N,1000] = h[N,32] @ fc_w[32,1000] + fc_b
// ---------------------------------------------------------------------------
#define FC_BN 128
__global__ __launch_bounds__(256) void fc_kernel(
    const float* __restrict__ h, const float* __restrict__ fcw,
    const float* __restrict__ fcb, float* __restrict__ out) {
  __shared__ float hs[FC_BN * HIDDEN];
  int base = blockIdx.x * FC_BN;
  int nvalid = min(FC_BN, N_NODES - base);

  int cnt4 = nvalid * HIDDEN / 4;
  const float4* s4 = (const float4*)(h + (size_t)base * HIDDEN);
  for (int i = threadIdx.x; i < cnt4; i += 256) ((float4*)hs)[i] = s4[i];
  __syncthreads();

#pragma unroll
  for (int c = 0; c < 4; ++c) {
    int j = c * 256 + threadIdx.x;
    if (j < NUM_HH) {
      float w[HIDDEN];
#pragma unroll
      for (int k = 0; k < HIDDEN; ++k) w[k] = fcw[k * NUM_HH + j];
      float bias = fcb[j];
      int n = 0;
      for (; n + 2 <= nvalid; n += 2) {
        float a0 = bias, a1 = bias;
#pragma unroll
        for (int k = 0; k < HIDDEN; ++k) {
          a0 = fmaf(hs[n * HIDDEN + k], w[k], a0);
          a1 = fmaf(hs[(n + 1) * HIDDEN + k], w[k], a1);
        }
        out[(size_t)(base + n) * NUM_HH + j] = a0;
        out[(size_t)(base + n + 1) * NUM_HH + j] = a1;
      }
      for (; n < nvalid; ++n) {
        float a0 = bias;
#pragma unroll
        for (int k = 0; k < HIDDEN; ++k)
          a0 = fmaf(hs[n * HIDDEN + k], w[k], a0);
        out[(size_t)(base + n) * NUM_HH + j] = a0;
      }
    }
  }
}

extern "C" void kernel_launch(void* const* d_in, const int* in_sizes, int n_in,
                              void* d_out, int out_size, void* d_ws,
                              size_t ws_size, hipStream_t stream) {
  const float* x = (const float*)d_in[0];
  const int* edge = (const int*)d_in[1];
  const float* w1_l = (const float*)d_in[2];
  const float* w1_r = (const float*)d_in[3];
  const float* b1 = (const float*)d_in[4];
  const float* w2_l = (const float*)d_in[5];
  const float* w2_r = (const float*)d_in[6];
  const float* b2 = (const float*)d_in[7];
  const float* fc_w = (const float*)d_in[8];
  const float* fc_b = (const float*)d_in[9];
  float* out = (float*)d_out;

  const int n_edges = in_sizes[1] / 2;
  const int* src = edge;
  const int* dst = edge + n_edges;

  // Workspace: packed/adj[E] | h1[N*32] | h2[N*32] | bucket_ptr | partials | row_ptr
  // counts/offs (3.2 MB) alias the head of h2 (dead before sage2 writes h2).
  // packed is sorted IN PLACE by bucket_sort and then serves as adj.
  unsigned* packed = (unsigned*)d_ws;
  float* h1 = (float*)(packed + n_edges);
  float* h2 = h1 + (size_t)N_NODES * HIDDEN;
  int* counts = (int*)h2;       // alias, dead after scan_local
  int* offs = counts + SCAN_N;  // alias, dead after passB_scatter
  int* bucket_ptr = (int*)(h2 + (size_t)N_NODES * HIDDEN);
  int* partials = bucket_ptr + NBUCK + 1;
  int* row_ptr = partials + S1_BLOCKS + 1;

  const int cepb = (n_edges + NCHUNK - 1) / NCHUNK;
  const int sgrid = N_NODES / 4;  // 25000 blocks, 4 node-waves each
  const int fgrid = (N_NODES + FC_BN - 1) / FC_BN;

  // ---- bucket partition + node-level counting sort (shared by both layers)
  passA_count<<<NCHUNK, 256, 0, stream>>>(dst, counts, n_edges, cepb);
  scan_local<<<S1_BLOCKS, 1024, 0, stream>>>(counts, offs, partials);
  scan_partials<<<1, 512, 0, stream>>>(partials);
  scan_add<<<S1_BLOCKS, 1024, 0, stream>>>(offs, partials, bucket_ptr, n_edges);
  passB_scatter<<<NCHUNK, 256, 0, stream>>>(src, dst, offs, packed, n_edges,
                                            cepb);
  bucket_sort<<<NBUCK, 512, 0, stream>>>(packed, bucket_ptr, row_ptr, n_edges);

  // ---- Layer 1 (CH=16): x -> h1 ----
  sage_fused<IN_CH><<<sgrid, 256, 0, stream>>>(x, row_ptr, (const int*)packed,
                                               w1_l, w1_r, b1, h1);
  // ---- Layer 2 (CH=32): h1 -> h2 ----
  sage_fused<HIDDEN><<<sgrid, 256, 0, stream>>>(h1, row_ptr, (const int*)packed,
                                                w2_l, w2_r, b2, h2);
  // ---- FC head ----
  fc_kernel<<<fgrid, 256, 0, stream>>>(h2, fc_w, fc_b, out);
}